// Round 10
// baseline (31758.786 us; speedup 1.0000x reference)
//
#include <hip/hip_runtime.h>
#include <math.h>

// 2-layer LSTM decoder, H=100, T=8192 encode + F=1024 future steps, fp32.
// V10: 2-WAY CELL-SPLIT PER STAGE -> 6 persistent blocks (6 CUs), 256 thr each.
// V6 measured 112 GB/s/CU weight streaming ~ the per-CU L2 ceiling (~135); the
// V9 LDS experiment regressed (bank conflicts + single LDS pipe). So: keep the
// V6-proven all-global streaming dot + flag discipline, halve per-CU traffic
// by splitting each stage by CELLS (each half owns complete i/f/g/o rows of
// its cells -> local c-update; only the 100-float h is exchanged, read
// directly from the existing rings).
//   blk 0 A0 : layer-1 cells 0-47  -> ring1a     blk 1 A1 : cells 48-99 -> ring1b
//   blk 2 A2a: pre2 rows cells 0-47 -> ring2a    blk 3 A2b: cells 48-99 -> ring2b
//   blk 4 B0 : layer-2 cells 0-47, partial y     blk 5 B1 : cells 48-99, partial y
// h1 exchange: A0 reads ring1b (A1's half) each step; mutual per-wave flags
// (publish-at-top BEFORE any wait -> skew <= 1 step, deadlock-free, and the
// mutual wait itself proves ring slots are consumed before overwrite).
// h2 exchange: 16-slot mailbox rings h2ra/h2rb + per-wave bw flags (same
// pattern). y: each B half publishes its partial (y0all incl. bias, y1all
// raw); A sums both in the future phase (chain depth unchanged); out[] is
// combined by B0 lagged LAG=64 steps, certified by B1's consumption flag
// b1_prog (flag=q proves y1all[<=q-2] ack'd, piggybacked on its top-of-iter
// vmcnt0).
// Sync primitives: V3..V6-proven. Relaxed agent atomics for data; ordering
// via s_waitcnt vmcnt only; NO agent fences (V2: whole-L2 wbl2/inv). Per-wave
// flags published at top-of-next-iteration after VMCNT0. A/B: raw s_barrier +
// lgkmcnt. A2: 1-deep pipeline, counted vmcnt(2) certify (28 vm-ops/iter).
// All flags monotone <= TOT+2 -> 0xAA poison sanitizes to 0.

#define HH 100
#define NT 256
#define SPIN_CAP 2000000u
#define LAG 64

#define OFF_AW0   0        // unsigned[4] A0 per-wave publish
#define OFF_AW1   128      // unsigned[4] A1
#define OFF_P2A   256      // unsigned[4] A2a
#define OFF_P2B   384      // unsigned[4] A2b
#define OFF_B0P   512      // unsigned    B0 consumption (also certifies y0all)
#define OFF_B1P   640      // unsigned    B1 consumption (also certifies y1all)
#define OFF_BY0   768      // unsigned    B0 future-y flag
#define OFF_BY1   896      // unsigned    B1 future-y flag
#define OFF_BW0   1024     // unsigned[4] B0 per-wave h2 publish
#define OFF_BW1   1152     // unsigned[4] B1
#define OFF_Y0ALL 4096     // float[TOT]  B0 partial y + bias (36,864B max)
#define OFF_Y1ALL 40960    // float[TOT]  B1 partial y
#define OFF_H2RA  77824    // float[16][48] B0 h2 mailbox
#define OFF_H2RB  80896    // float[16][52] B1 h2 mailbox
#define OFF_RING  98304    // ring1a[S][48] ring1b[S][52] ring2a[S][192] ring2b[S][208]

#define VMCNT0() asm volatile("s_waitcnt vmcnt(0)" ::: "memory")
#define VMCNT2() asm volatile("s_waitcnt vmcnt(2)" ::: "memory")
#define LGKM0()  asm volatile("s_waitcnt lgkmcnt(0)" ::: "memory")
#define CLOB()   asm volatile("" ::: "memory")

__device__ __forceinline__ float rl(float v, int k) {
    return __int_as_float(__builtin_amdgcn_readlane(__float_as_int(v), k));
}
__device__ __forceinline__ unsigned san(unsigned v) { return v > 0x00FFFFFFu ? 0u : v; }
__device__ __forceinline__ unsigned ldu(const unsigned* p) {
    return san(__hip_atomic_load((unsigned*)p, __ATOMIC_RELAXED, __HIP_MEMORY_SCOPE_AGENT));
}
__device__ __forceinline__ void stu(unsigned* p, unsigned v) {
    __hip_atomic_store(p, v, __ATOMIC_RELAXED, __HIP_MEMORY_SCOPE_AGENT);
}
__device__ __forceinline__ float ld_f(const float* p) {
    return __hip_atomic_load((float*)p, __ATOMIC_RELAXED, __HIP_MEMORY_SCOPE_AGENT);
}
__device__ __forceinline__ void st_wt(float* p, float v) {
    __hip_atomic_store(p, v, __ATOMIC_RELAXED, __HIP_MEMORY_SCOPE_AGENT);
}
__device__ __forceinline__ void wait_ge(unsigned* p, unsigned need, unsigned& cache) {
    if (cache >= need) return;
    unsigned s = 0;
    do { cache = ldu(p); } while (cache < need && ++s < SPIN_CAP);
    VMCNT0();
}
__device__ __forceinline__ void wait_min4(unsigned* q, unsigned need, unsigned& cache) {
    if (cache >= need) return;
    unsigned s = 0;
    for (;;) {
        unsigned m0 = ldu(q), m1 = ldu(q + 1), m2 = ldu(q + 2), m3 = ldu(q + 3);
        unsigned a = m0 < m1 ? m0 : m1, b = m2 < m3 ? m2 : m3;
        cache = a < b ? a : b;
        if (cache >= need || ++s > SPIN_CAP) break;
    }
    VMCNT0();
}
// Raw workgroup barrier: LDS drain only (ring stores stay in flight).
__device__ __forceinline__ void bar() {
    LGKM0();
    __builtin_amdgcn_s_barrier();
    CLOB();
}
__device__ __forceinline__ float fast_sigm(float x) {
    return __builtin_amdgcn_rcpf(1.0f + __expf(-x));
}
__device__ __forceinline__ float fast_tanh(float x) {
    return fmaf(-2.0f, __builtin_amdgcn_rcpf(1.0f + __expf(2.0f * x)), 1.0f);
}

// ---- V6-proven dot: 25 float4 chunks streamed from global `grow` ----
#define REP25(M) M(0) M(1) M(2) M(3) M(4) M(5) M(6) M(7) M(8) M(9) M(10) M(11) \
                 M(12) M(13) M(14) M(15) M(16) M(17) M(18) M(19) M(20) M(21) M(22) M(23) M(24)
#define DOTC(i) { \
    const float hsv = ((i) < 16) ? hv0 : hv1; \
    const int kb = ((i) < 16) ? (4 * (i)) : (4 * ((i) - 16)); \
    float4 Wc = grow[i]; \
    float h0 = rl(hsv, kb), h1 = rl(hsv, kb + 1), h2 = rl(hsv, kb + 2), h3 = rl(hsv, kb + 3); \
    a0 = fmaf(Wc.x, h0, a0); a1 = fmaf(Wc.y, h1, a1); \
    a0 = fmaf(Wc.z, h2, a0); a1 = fmaf(Wc.w, h3, a1); \
}

extern "C" __global__ void __launch_bounds__(NT, 1)
decoder_kernel(const float* __restrict__ input,
               const float* __restrict__ enc_h,
               const float* __restrict__ enc_c,
               const float* __restrict__ w_ih1,
               const float* __restrict__ w_hh1,
               const float* __restrict__ b_ih1,
               const float* __restrict__ b_hh1,
               const float* __restrict__ w_ih2,
               const float* __restrict__ w_hh2,
               const float* __restrict__ b_ih2,
               const float* __restrict__ b_hh2,
               const float* __restrict__ w_lin,
               const float* __restrict__ b_lin,
               float* __restrict__ out,
               char* __restrict__ ws,
               int T, int F, int S)
{
    const int tid = threadIdx.x;
    const int l = tid & 63;
    const int w = tid >> 6;
    const int m = l & 15;
    float* ring1a = (float*)(ws + OFF_RING);
    float* ring1b = ring1a + (size_t)S * 48;
    float* ring2a = ring1b + (size_t)S * 52;
    float* ring2b = ring2a + (size_t)S * 192;
    float* y0all = (float*)(ws + OFF_Y0ALL);
    float* y1all = (float*)(ws + OFF_Y1ALL);
    unsigned* p2a = (unsigned*)(ws + OFF_P2A);
    unsigned* p2b = (unsigned*)(ws + OFF_P2B);
    const int smask = S - 1;
    const int TOT = T + F;
    const int bid = blockIdx.x;

    if (bid < 2) {
        // ================= A half: layer-1 recurrence =================
        const int half = bid;
        const int cbase = half ? 48 : 0;
        const int ccnt  = half ? 52 : 48;
        const int myW   = ccnt;
        const int peerW = half ? 48 : 52;
        float* myRing   = half ? ring1b : ring1a;
        float* peerRing = half ? ring1a : ring1b;
        unsigned* myAw   = (unsigned*)(ws + (half ? OFF_AW1 : OFF_AW0));
        unsigned* peerAw = (unsigned*)(ws + (half ? OFF_AW0 : OFF_AW1));
        unsigned* by0 = (unsigned*)(ws + OFF_BY0);
        unsigned* by1 = (unsigned*)(ws + OFF_BY1);

        __shared__ __align__(16) float h1s[2][64];
        const int local = 16 * w + m;
        const bool valid = local < ccnt;
        const int cell = cbase + (valid ? local : 0);
        const int gate = l >> 4;
        const bool c_lane = (gate == 0) && valid;
        const int j = valid ? (cell + 100 * gate) : 0;
        const float4* grow = (const float4*)(w_hh1 + (size_t)j * HH);
        const float wx = w_ih1[j];
        const float bi = b_ih1[j] + b_hh1[j];
        float cst = c_lane ? enc_c[cell] : 0.f;
        if (tid < 64) { h1s[0][tid] = 0.f; h1s[1][tid] = 0.f; }
        __syncthreads();

        unsigned cg1 = 0, cg2 = 0, cpeer = 0, cy0 = 0, cy1 = 0;
        for (int t = 0; t < TOT; ++t) {
            VMCNT0();                                   // own ring stores of t-1 ack'd
            if (l == 0 && t > 0) stu(&myAw[w], (unsigned)t);   // slots <= t-1 valid
            float x = 0.f;
            if (t < T) x = input[t];
            // ring overwrite guard (A2a+A2b both read my full-h half)
            if (t >= S) { wait_min4(p2a, (unsigned)(t - S + 1), cg1);
                          wait_min4(p2b, (unsigned)(t - S + 1), cg2); }
            float hv0, hv1;
            if (t == 0) {                               // h1(-1) = enc_h
                hv0 = enc_h[l];
                hv1 = (l < 36) ? enc_h[64 + l] : 0.f;
            } else {
                wait_min4(peerAw, (unsigned)t, cpeer);  // peer h(t-1) published
                const float* pr = peerRing + (size_t)((t - 1) & smask) * peerW;
                if (half == 0) {
                    hv0 = (l < 48) ? h1s[t & 1][l] : ld_f(pr + (l - 48));
                    hv1 = (l < 36) ? ld_f(pr + (16 + l)) : 0.f;
                } else {
                    hv0 = (l < 48) ? ld_f(pr + l) : h1s[t & 1][l - 48];
                    hv1 = (l < 36) ? h1s[t & 1][16 + l] : 0.f;
                }
            }
            float a0 = 0.f, a1 = 0.f;
            REP25(DOTC)
            float acc = bi + a0 + a1;
            if (t >= T) {                               // future: dot done, wait y(t-1)
                wait_ge(by0, (unsigned)(t - T + 1), cy0);
                wait_ge(by1, (unsigned)(t - T + 1), cy1);
                x = ld_f(y0all + (t - 1)) + ld_f(y1all + (t - 1));
            }
            acc = fmaf(x, wx, acc);
            float v = (gate == 2) ? fast_tanh(acc) : fast_sigm(acc);
            float gf = __shfl(v, m + 16);
            float gg = __shfl(v, m + 32);
            float go = __shfl(v, m + 48);
            if (c_lane) {
                cst = fmaf(gf, cst, v * gg);
                float h = go * fast_tanh(cst);
                h1s[(t + 1) & 1][local] = h;
                st_wt(myRing + (size_t)(t & smask) * myW + local, h);
            }
            bar();
        }
        VMCNT0();
        if (l == 0) stu(&myAw[w], (unsigned)TOT);
    } else if (bid < 4) {
        // ================= A2 half: pre2 = w_ih2*h1 + biases =================
        const int half = bid - 2;
        const int ccnt = half ? 52 : 48;
        const int cbase = half ? 48 : 0;
        const bool valid = l < ccnt;
        const int gate = w;                       // wave = gate
        const int cell = cbase + (valid ? l : 0);
        const int j = valid ? (cell + 100 * gate) : 0;
        const int oidx = (valid ? l : 0) + ccnt * gate;
        float* myR2 = half ? ring2b : ring2a;
        const int r2W = half ? 208 : 192;
        unsigned* myP2  = (unsigned*)(ws + (half ? OFF_P2B : OFF_P2A));
        unsigned* bprog = (unsigned*)(ws + (half ? OFF_B1P : OFF_B0P));
        unsigned* aw0 = (unsigned*)(ws + OFF_AW0);
        unsigned* aw1 = (unsigned*)(ws + OFF_AW1);
        const float4* grow = (const float4*)(w_ih2 + (size_t)j * HH);
        const float bi = b_ih2[j] + b_hh2[j];

        unsigned ca0 = 0, ca1 = 0, cb = 0;
        // ---- prologue: load h1 slot 0
        wait_min4(aw0, 1u, ca0);
        wait_min4(aw1, 1u, ca1);
        float cv0 = (l < 48) ? ld_f(ring1a + l) : ld_f(ring1b + (l - 48));
        float cv1 = (l < 36) ? ld_f(ring1b + (16 + l)) : 0.f;
        // ---- pipelined encode (V6 clone): iter t stores slot t-1, prefetches t.
        // 28 vm-ops/iter -> vmcnt(2) at top certifies slot t-3's store.
        for (int t = 1; t < T; ++t) {
            VMCNT2();
            if (l == 0 && t >= 3) stu(&myP2[w], (unsigned)(t - 2));  // slots <= t-3 valid
            if (t - 1 >= S) wait_ge(bprog, (unsigned)(t - S), cb);   // overwrite guard
            wait_min4(aw0, (unsigned)(t + 1), ca0);                  // slot t readable
            wait_min4(aw1, (unsigned)(t + 1), ca1);
            const float* ra = ring1a + (size_t)(t & smask) * 48;
            const float* rb = ring1b + (size_t)(t & smask) * 52;
            float nv0 = (l < 48) ? ld_f(ra + l) : ld_f(rb + (l - 48));
            float nv1 = (l < 36) ? ld_f(rb + (16 + l)) : 0.f;
            float hv0 = cv0, hv1 = cv1;
            float a0 = 0.f, a1 = 0.f;
            REP25(DOTC)                                              // h(t-1)
            float* wp = myR2 + (size_t)((t - 1) & smask) * r2W;
            if (valid) st_wt(wp + oidx, bi + a0 + a1);
            cv0 = nv0; cv1 = nv1;
        }
        // ---- boundary: drain, slot T-1 straight.
        VMCNT0();
        if (l == 0) stu(&myP2[w], (unsigned)(T - 1));
        {
            if (T - 1 >= S) wait_ge(bprog, (unsigned)(T - S), cb);
            float hv0 = cv0, hv1 = cv1;
            float a0 = 0.f, a1 = 0.f;
            REP25(DOTC)
            float* wp = myR2 + (size_t)((T - 1) & smask) * r2W;
            if (valid) st_wt(wp + oidx, bi + a0 + a1);
        }
        VMCNT0();
        if (l == 0) stu(&myP2[w], (unsigned)T);
        // ---- future: straight mode.
        for (int t = T; t < TOT; ++t) {
            if (t >= S) wait_ge(bprog, (unsigned)(t - S + 1), cb);
            wait_min4(aw0, (unsigned)(t + 1), ca0);
            wait_min4(aw1, (unsigned)(t + 1), ca1);
            const float* ra = ring1a + (size_t)(t & smask) * 48;
            const float* rb = ring1b + (size_t)(t & smask) * 52;
            float hv0 = (l < 48) ? ld_f(ra + l) : ld_f(rb + (l - 48));
            float hv1 = (l < 36) ? ld_f(rb + (16 + l)) : 0.f;
            float a0 = 0.f, a1 = 0.f;
            REP25(DOTC)
            float* wp = myR2 + (size_t)(t & smask) * r2W;
            if (valid) st_wt(wp + oidx, bi + a0 + a1);
            VMCNT0();
            if (l == 0) stu(&myP2[w], (unsigned)(t + 1));
        }
    } else {
        // ================= B half: layer-2 recurrence + partial y =================
        const int half = bid - 4;
        const int cbase = half ? 48 : 0;
        const int ccnt = half ? 52 : 48;
        const int myW = ccnt, peerW = half ? 48 : 52;
        float* myH2R   = (float*)(ws + (half ? OFF_H2RB : OFF_H2RA));
        float* peerH2R = (float*)(ws + (half ? OFF_H2RA : OFF_H2RB));
        unsigned* myBw   = (unsigned*)(ws + (half ? OFF_BW1 : OFF_BW0));
        unsigned* peerBw = (unsigned*)(ws + (half ? OFF_BW0 : OFF_BW1));
        unsigned* myBp = (unsigned*)(ws + (half ? OFF_B1P : OFF_B0P));
        unsigned* myBy = (unsigned*)(ws + (half ? OFF_BY1 : OFF_BY0));
        unsigned* b1p  = (unsigned*)(ws + OFF_B1P);
        float* myYall = half ? y1all : y0all;
        float* myR2 = half ? ring2b : ring2a;
        const int r2W = half ? 208 : 192;
        unsigned* p2h = (unsigned*)(ws + (half ? OFF_P2B : OFF_P2A));

        __shared__ __align__(16) float h2s[2][64];
        __shared__ float yw[2][4];
        const int local = 16 * w + m;
        const bool valid = local < ccnt;
        const int cell = cbase + (valid ? local : 0);
        const int gate = l >> 4;
        const bool c_lane = (gate == 0) && valid;
        const int j = valid ? (cell + 100 * gate) : 0;
        const int pidx = (valid ? local : 0) + ccnt * gate;
        const float4* grow = (const float4*)(w_hh2 + (size_t)j * HH);
        const float wl = c_lane ? w_lin[cell] : 0.f;
        const float bl = half ? 0.f : b_lin[0];   // bias folded into B0's partial
        float cst = 0.f;
        if (tid < 64) { h2s[0][tid] = 0.f; h2s[1][tid] = 0.f; }
        if (tid < 8) yw[tid >> 2][tid & 3] = 0.f;
        __syncthreads();

        unsigned cp = 0, cpe = 0, cb1g = 0;
        for (int u = 0; u < TOT; ++u) {
            VMCNT0();                                  // h2 mailbox stores of u-1 ack'd
            if (l == 0 && u > 0) stu(&myBw[w], (unsigned)u);
            if (tid == 0 && u > 0) {
                stu(myBp, (unsigned)u);                // ring2 slot u-1 consumed; y<=u-2 cert'd
                const float* yq = yw[(u - 1) & 1];
                float yp = yq[0] + yq[1] + yq[2] + yq[3] + bl;
                st_wt(&myYall[u - 1], yp);
                if (u >= T) { VMCNT0(); stu(myBy, (unsigned)(u - T + 1)); }  // immediate for A
                if (half == 0 && u - 1 >= LAG) {       // lagged out[] combine
                    int v = u - 1 - LAG;
                    wait_ge(b1p, (unsigned)(v + 2), cb1g);   // y1all[<=v] certified
                    out[v] = ld_f(y0all + v) + ld_f(y1all + v);
                }
            }
            float hv0, hv1;
            if (u == 0) { hv0 = 0.f; hv1 = 0.f; }      // h2(-1) = 0
            else {
                wait_min4(peerBw, (unsigned)u, cpe);
                const float* pr = peerH2R + (size_t)((u - 1) & 15) * peerW;
                if (half == 0) {
                    hv0 = (l < 48) ? h2s[u & 1][l] : ld_f(pr + (l - 48));
                    hv1 = (l < 36) ? ld_f(pr + (16 + l)) : 0.f;
                } else {
                    hv0 = (l < 48) ? ld_f(pr + l) : h2s[u & 1][l - 48];
                    hv1 = (l < 36) ? h2s[u & 1][16 + l] : 0.f;
                }
            }
            float pre = 0.f;
            float a0 = 0.f, a1 = 0.f;
            if (u < T) {      // encode: wait first, pre2 load hides under dot
                wait_min4(p2h, (unsigned)(u + 1), cp);
                const float* pp = myR2 + (size_t)(u & smask) * r2W;
                pre = ld_f(pp + pidx);
                REP25(DOTC)
            } else {          // future: local dot first, then wait
                REP25(DOTC)
                wait_min4(p2h, (unsigned)(u + 1), cp);
                const float* pp = myR2 + (size_t)(u & smask) * r2W;
                pre = ld_f(pp + pidx);
            }
            float acc = pre + a0 + a1;
            float v = (gate == 2) ? fast_tanh(acc) : fast_sigm(acc);
            float gf = __shfl(v, m + 16);
            float gg = __shfl(v, m + 32);
            float go = __shfl(v, m + 48);
            float py = 0.f;
            if (c_lane) {
                cst = fmaf(gf, cst, v * gg);
                float h = go * fast_tanh(cst);
                h2s[(u + 1) & 1][local] = h;
                st_wt(myH2R + (size_t)(u & 15) * myW + local, h);
                py = h * wl;
            }
            py += __shfl_down(py, 8);
            py += __shfl_down(py, 4);
            py += __shfl_down(py, 2);
            py += __shfl_down(py, 1);
            if (l == 0) yw[u & 1][w] = py;
            bar();
        }
        // ---- post-loop: final partial + drain out[] tail
        if (tid == 0) {
            const float* yq = yw[(TOT - 1) & 1];
            float yp = yq[0] + yq[1] + yq[2] + yq[3] + bl;
            st_wt(&myYall[TOT - 1], yp);
            VMCNT0();
            stu(myBp, (unsigned)(TOT + 2));            // certifies all of myYall
            if (half == 0) {
                unsigned cfin = 0;
                wait_ge(b1p, (unsigned)(TOT + 2), cfin);
                for (int v2 = TOT - 1 - LAG; v2 < TOT; ++v2)
                    out[v2] = ld_f(y0all + v2) + ld_f(y1all + v2);
            }
        }
    }
}

extern "C" void kernel_launch(void* const* d_in, const int* in_sizes, int n_in,
                              void* d_out, int out_size, void* d_ws, size_t ws_size,
                              hipStream_t stream) {
    const float* input = (const float*)d_in[0];
    const float* enc_h = (const float*)d_in[1];
    const float* enc_c = (const float*)d_in[2];
    const float* w_ih1 = (const float*)d_in[3];
    const float* w_hh1 = (const float*)d_in[4];
    const float* b_ih1 = (const float*)d_in[5];
    const float* b_hh1 = (const float*)d_in[6];
    const float* w_ih2 = (const float*)d_in[7];
    const float* w_hh2 = (const float*)d_in[8];
    const float* b_ih2 = (const float*)d_in[9];
    const float* b_hh2 = (const float*)d_in[10];
    const float* w_lin = (const float*)d_in[11];
    const float* b_lin = (const float*)d_in[12];
    (void)n_in;

    int T = in_sizes[0];
    int F = out_size - T;
    if (F < 0) F = 0;

    // rings: 500 floats (2000 B) per slot total; 2x headroom like prior rounds.
    int S = 16;
    while ((size_t)OFF_RING + (size_t)S * 4000 <= ws_size && S < 8192)
        S <<= 1;

    decoder_kernel<<<dim3(6), dim3(NT), 0, stream>>>(
        input, enc_h, enc_c, w_ih1, w_hh1, b_ih1, b_hh1,
        w_ih2, w_hh2, b_ih2, b_hh2, w_lin, b_lin,
        (float*)d_out, (char*)d_ws, T, F, S);
}

// Round 11
// 26356.104 us; speedup vs baseline: 1.2050x; 1.2050x over previous
//
#include <hip/hip_runtime.h>
#include <hip/hip_fp16.h>
#include <math.h>

// 2-layer LSTM decoder, H=100, T=8192 encode + F=1024 future steps, fp32 state.
// Three persistent blocks (3 CUs), 256 threads (4 waves) each, 2 rows/thread:
//   block 0 (A) : layer-1 recurrence. gates1 = w_ih1*x + w_hh1*h1 + b. h1 -> ring1.
//   block 1 (A2): feed-forward pre2 = w_ih2*h1 + biases. ring1 -> ring2.
//   block 2 (B) : layer-2 recurrence gates2 = pre2 + w_hh2*h2; y = h2.w_lin + b.
//
// V11: FP16 WEIGHT STREAMING. Measured wall (V5, best at 16.0ms): 160KB fp32
// weights/CU/step at ~92GB/s/CU L2 = ~1.74us/step pacer. All structural
// levers measured dead: registers (V3-V6: RA remats/spills), LDS (V9: pipe +
// conflicts, +87%), multi-CU recurrence split (V10: LLC h-exchange on the
// critical path, +90%). Remaining lever: bytes. Each block converts ITS OWN
// matrix to fp16 once at startup (rows padded 100->104 halves = 208B,
// 16B-aligned; pad weights 0, matching broadcast lanes provably 0). Dot
// streams 13 x float4 (8 halves each) = 83.2KB/CU/step, cvt + fp32 FMA
// (accumulation exact fp32). Numerics: 4.9e-4 rel/weight -> gate err ~1.5e-4
// -> saturating-gate contraction (V3-V9 showed absmax 0.0 under reordering)
// -> y err ~1e-4 << 2.75e-3 threshold. Biases/x-column/w_lin/rings stay fp32.
//
// Sync design (V3..V6-proven, byte-identical):
//  * Cross-CU data via relaxed agent atomics; ordering via s_waitcnt vmcnt only
//    (producer: vmcnt(0) before flag store; consumer: vmcnt(0) after flag obs).
//    NO agent fences (whole-L2 wbl2/inv = V2 regression).
//  * Per-wave flags aw[4]/p2w[4]; consumers take min4. Producers publish at
//    top-of-next-iteration (store acks aged ~1 iter -> vmcnt cheap).
//  * A/B: raw s_barrier + lgkmcnt(0) (LDS-only drain; ring stores in flight).
//    A2: counted vmcnt(2) certify (29 vm-ops/iter -> slot t-3 store >=58 ops
//    back), 1-deep prefetch pipeline in encode, straight mode in future.
//  * Flags monotone <= 9217 -> 0xAA workspace poison sanitizes to 0.
//  * Converted weights live in ws (re-converted every launch -> poison-safe).

#define HH 100
#define NT 256
#define ROWS 400
#define RPAD 104           // padded row length in halves (208B, 16B-aligned)
#define SPIN_CAP 2000000u

#define OFF_AW     0       // unsigned aw[4]  : A per-wave publish counters
#define OFF_P2W    128     // unsigned p2w[4] : A2 per-wave publish counters
#define OFF_BPROG  256     // unsigned        : B consumption counter
#define OFF_YPROG  384     // unsigned        : y produced counter
#define OFF_YSLOT  512     // float[F+1]
#define OFF_WC     4096    // 3 x 400x104 halves = 249,600 B converted weights
#define OFF_RING   262144

#define VMCNT0() asm volatile("s_waitcnt vmcnt(0)" ::: "memory")
#define VMCNT2() asm volatile("s_waitcnt vmcnt(2)" ::: "memory")
#define LGKM0()  asm volatile("s_waitcnt lgkmcnt(0)" ::: "memory")
#define CLOB()   asm volatile("" ::: "memory")

__device__ __forceinline__ float rl(float v, int k) {
    return __int_as_float(__builtin_amdgcn_readlane(__float_as_int(v), k));
}
__device__ __forceinline__ unsigned san(unsigned v) { return v > 0x00FFFFFFu ? 0u : v; }
__device__ __forceinline__ unsigned ldu(const unsigned* p) {
    return san(__hip_atomic_load((unsigned*)p, __ATOMIC_RELAXED, __HIP_MEMORY_SCOPE_AGENT));
}
__device__ __forceinline__ void stu(unsigned* p, unsigned v) {
    __hip_atomic_store(p, v, __ATOMIC_RELAXED, __HIP_MEMORY_SCOPE_AGENT);
}
__device__ __forceinline__ float ld_f(const float* p) {
    return __hip_atomic_load((float*)p, __ATOMIC_RELAXED, __HIP_MEMORY_SCOPE_AGENT);
}
__device__ __forceinline__ void st_wt(float* p, float v) {
    __hip_atomic_store(p, v, __ATOMIC_RELAXED, __HIP_MEMORY_SCOPE_AGENT);
}
__device__ __forceinline__ void wait_ge(unsigned* p, unsigned need, unsigned& cache) {
    if (cache >= need) return;
    unsigned s = 0;
    do { cache = ldu(p); } while (cache < need && ++s < SPIN_CAP);
    VMCNT0();
}
__device__ __forceinline__ void wait_min4(unsigned* q, unsigned need, unsigned& cache) {
    if (cache >= need) return;
    unsigned s = 0;
    for (;;) {
        unsigned m0 = ldu(q), m1 = ldu(q + 1), m2 = ldu(q + 2), m3 = ldu(q + 3);
        unsigned a = m0 < m1 ? m0 : m1, b = m2 < m3 ? m2 : m3;
        cache = a < b ? a : b;
        if (cache >= need || ++s > SPIN_CAP) break;
    }
    VMCNT0();
}
// Raw workgroup barrier: LDS drain only (ring stores stay in flight).
__device__ __forceinline__ void bar() {
    LGKM0();
    __builtin_amdgcn_s_barrier();
    CLOB();
}
__device__ __forceinline__ float fast_sigm(float x) {
    return __builtin_amdgcn_rcpf(1.0f + __expf(-x));
}
__device__ __forceinline__ float fast_tanh(float x) {
    return fmaf(-2.0f, __builtin_amdgcn_rcpf(1.0f + __expf(2.0f * x)), 1.0f);
}

// ---- fp16 weight dot: 13 chunks x 8 halves x 2 rows ----
// chunk c covers h[8c..8c+7]; c<8 broadcasts from hv0 (lanes 8c..), c>=8 from
// hv1 (lanes 8c-64..). Chunk 12 covers k=96..103: weights k>=100 are 0 (pad)
// and rl(hv1,36..39) lanes hold 0 (h state slots 100..127 initialized 0;
// ring-sourced hv1 is masked (l<36)). Accumulation fp32 (a0,a1,b0,b1).
#define REP13(M) M(0) M(1) M(2) M(3) M(4) M(5) M(6) M(7) M(8) M(9) M(10) M(11) M(12)
#define DOTC(c) { \
    const float hsv = ((c) < 8) ? hv0 : hv1; \
    const int kb = ((c) < 8) ? (8 * (c)) : (8 * (c) - 64); \
    float4 Wa = w0p[c]; \
    float4 Wb = w1p[c]; \
    const __half2* pa = (const __half2*)&Wa; \
    const __half2* pb = (const __half2*)&Wb; \
    float h0 = rl(hsv, kb),     h1 = rl(hsv, kb + 1), h2 = rl(hsv, kb + 2), h3 = rl(hsv, kb + 3); \
    float h4 = rl(hsv, kb + 4), h5 = rl(hsv, kb + 5), h6 = rl(hsv, kb + 6), h7 = rl(hsv, kb + 7); \
    a0 = fmaf(__low2float(pa[0]),  h0, a0); a1 = fmaf(__high2float(pa[0]), h1, a1); \
    a0 = fmaf(__low2float(pa[1]),  h2, a0); a1 = fmaf(__high2float(pa[1]), h3, a1); \
    a0 = fmaf(__low2float(pa[2]),  h4, a0); a1 = fmaf(__high2float(pa[2]), h5, a1); \
    a0 = fmaf(__low2float(pa[3]),  h6, a0); a1 = fmaf(__high2float(pa[3]), h7, a1); \
    b0 = fmaf(__low2float(pb[0]),  h0, b0); b1 = fmaf(__high2float(pb[0]), h1, b1); \
    b0 = fmaf(__low2float(pb[1]),  h2, b0); b1 = fmaf(__high2float(pb[1]), h3, b1); \
    b0 = fmaf(__low2float(pb[2]),  h4, b0); b1 = fmaf(__high2float(pb[2]), h5, b1); \
    b0 = fmaf(__low2float(pb[3]),  h6, b0); b1 = fmaf(__high2float(pb[3]), h7, b1); \
}

extern "C" __global__ void __launch_bounds__(NT)
__attribute__((amdgpu_waves_per_eu(1, 1)))
decoder_kernel(const float* __restrict__ input,
               const float* __restrict__ enc_h,
               const float* __restrict__ enc_c,
               const float* __restrict__ w_ih1,
               const float* __restrict__ w_hh1,
               const float* __restrict__ b_ih1,
               const float* __restrict__ b_hh1,
               const float* __restrict__ w_ih2,
               const float* __restrict__ w_hh2,
               const float* __restrict__ b_ih2,
               const float* __restrict__ b_hh2,
               const float* __restrict__ w_lin,
               const float* __restrict__ b_lin,
               float* __restrict__ out,
               char* __restrict__ ws,
               int T, int F, int S)
{
    const int tid = threadIdx.x;
    const int l = tid & 63;
    const int w = tid >> 6;
    unsigned* aw     = (unsigned*)(ws + OFF_AW);
    unsigned* p2w    = (unsigned*)(ws + OFF_P2W);
    unsigned* b_prog = (unsigned*)(ws + OFF_BPROG);
    unsigned* y_prog = (unsigned*)(ws + OFF_YPROG);
    float* y_slot = (float*)(ws + OFF_YSLOT);
    float* ring1  = (float*)(ws + OFF_RING);
    float* ring2  = ring1 + (size_t)S * HH;
    const int smask = S - 1;
    const int TOT = T + F;
    const int bid = blockIdx.x;

    // ---- one-time: convert THIS block's matrix to fp16 (padded rows) ----
    __half* wc = (__half*)(ws + OFF_WC) + (size_t)bid * (ROWS * RPAD);
    {
        const float* wsrc = (bid == 0) ? w_hh1 : (bid == 1) ? w_ih2 : w_hh2;
        for (int i = tid; i < ROWS * RPAD; i += NT) {
            int r = i / RPAD, c = i - r * RPAD;
            wc[i] = __float2half(c < HH ? wsrc[r * HH + c] : 0.f);
        }
    }

    // Gate lane mapping (A and B): wave w owns cells 25w..25w+24.
    // lanes 0-24: rows cell (i), cell+100 (f); lanes 32-56: cell+200 (g), cell+300 (o).
    const bool gi_lane = (l < 25);
    const bool go_lane = (l >= 32 && l < 57);
    const int cell = 25 * w + (gi_lane ? l : (go_lane ? (l - 32) : 0));
    const int gj0 = gi_lane ? cell : (go_lane ? cell + 200 : 0);
    const int gj1 = gi_lane ? cell + 100 : (go_lane ? cell + 300 : 0);

    if (bid == 0) {
        // ================= A: layer-1 recurrence =================
        __shared__ __align__(16) float h1s[2][128];
        const float4* w0p = (const float4*)(wc + (size_t)gj0 * RPAD);
        const float4* w1p = (const float4*)(wc + (size_t)gj1 * RPAD);
        const float wx0 = w_ih1[gj0];
        const float wx1 = w_ih1[gj1];
        const float bi0 = b_ih1[gj0] + b_hh1[gj0];
        const float bi1 = b_ih1[gj1] + b_hh1[gj1];
        float cst = gi_lane ? enc_c[cell] : 0.f;
        if (tid < 128) {
            h1s[0][tid] = (tid < HH) ? enc_h[tid] : 0.f;
            h1s[1][tid] = 0.f;
        }
        __syncthreads();   // publishes fp16 conversion (vmcnt0) + h1s init

        unsigned cp2 = 0, cy = 0;
        for (int t = 0; t < TOT; ++t) {
            // publish slot t-1: ring1 stores aged ~1 iteration -> vmcnt(0) cheap.
            VMCNT0();
            if (l == 0 && t > 0) stu(&aw[w], (unsigned)t);     // slots <= t-1 valid
            float x = 0.f;
            if (t < T) x = input[t];
            // ring1 overwrite guard: A2 consumed slot t-S when min(p2w) >= t-S+1
            if (t >= S) wait_min4(p2w, (unsigned)(t - S + 1), cp2);
            float hv0 = h1s[t & 1][l];
            float hv1 = h1s[t & 1][64 + l];    // slots 100-127 stay 0
            float a0 = 0.f, a1 = 0.f, b0 = 0.f, b1 = 0.f;
            REP13(DOTC)
            float accA = bi0 + a0 + a1;
            float accB = bi1 + b0 + b1;
            if (t >= T) {                       // future: dot done, now wait for y
                wait_ge(y_prog, (unsigned)(t - T + 1), cy);
                x = ld_f(&y_slot[t - T]);
            }
            accA = fmaf(x, wx0, accA);
            accB = fmaf(x, wx1, accB);
            float vA = go_lane ? fast_tanh(accA) : fast_sigm(accA);  // i or g
            float vB = fast_sigm(accB);                              // f or o
            float gg = __shfl_xor(vA, 32);
            float go = __shfl_xor(vB, 32);
            if (gi_lane) {
                cst = fmaf(vB, cst, vA * gg);
                float h = go * fast_tanh(cst);
                h1s[(t + 1) & 1][cell] = h;
                st_wt(&ring1[(size_t)(t & smask) * HH + cell], h);
            }
            bar();    // LDS-only drain; ring1 stores stay in flight across it
        }
        VMCNT0();
        if (l == 0) stu(&aw[w], (unsigned)TOT);
    } else if (bid == 1) {
        // ===== A2: pre2 = w_ih2*h1 + biases. 4 independent waves, no barriers. =====
        const bool has2 = tid < (ROWS - NT);   // tid < 144 owns a second row
        const int j0 = tid, j1 = has2 ? NT + tid : 0;
        const float4* w0p = (const float4*)(wc + (size_t)j0 * RPAD);
        const float4* w1p = (const float4*)(wc + (size_t)j1 * RPAD);
        const float bi0 = b_ih2[j0] + b_hh2[j0];
        const float bi1 = b_ih2[j1] + b_hh2[j1];
        __syncthreads();   // publishes fp16 conversion (rows written by other threads)

        unsigned ca = 0, cb = 0;
        // ---- prologue: load slot 0
        wait_min4(aw, 1u, ca);
        float cv0 = ld_f(ring1 + l);
        float cv1 = (l < 36) ? ld_f(ring1 + 64 + l) : 0.f;
        // ---- pipelined encode: iter t stores slot t-1, prefetches slot t.
        // 29 vm-ops/iter -> vmcnt(2) at top certifies slot t-3's store (>=58 back).
        for (int t = 1; t < T; ++t) {
            VMCNT2();
            if (l == 0 && t >= 3) stu(&p2w[w], (unsigned)(t - 2));  // slots <= t-3 valid
            if (t - 1 >= S) wait_ge(b_prog, (unsigned)(t - S), cb); // overwrite guard
            wait_min4(aw, (unsigned)(t + 1), ca);                   // slot t readable
            const float* rp = ring1 + (size_t)(t & smask) * HH;
            float nv0 = ld_f(rp + l);
            float nv1 = (l < 36) ? ld_f(rp + 64 + l) : 0.f;
            float hv0 = cv0, hv1 = cv1;
            float a0 = 0.f, a1 = 0.f, b0 = 0.f, b1 = 0.f;
            REP13(DOTC)                                             // h(t-1)
            float* wpp = ring2 + (size_t)((t - 1) & smask) * ROWS;
            st_wt(wpp + j0, bi0 + a0 + a1);
            if (has2) st_wt(wpp + j1, bi1 + b0 + b1);
            cv0 = nv0; cv1 = nv1;
        }
        // ---- boundary: drain pipeline, then slot T-1 straight.
        VMCNT0();
        if (l == 0) stu(&p2w[w], (unsigned)(T - 1));                // slots <= T-2 valid
        {
            if (T - 1 >= S) wait_ge(b_prog, (unsigned)(T - S), cb);
            float hv0 = cv0, hv1 = cv1;
            float a0 = 0.f, a1 = 0.f, b0 = 0.f, b1 = 0.f;
            REP13(DOTC)                                             // h(T-1)
            float* wpp = ring2 + (size_t)((T - 1) & smask) * ROWS;
            st_wt(wpp + j0, bi0 + a0 + a1);
            if (has2) st_wt(wpp + j1, bi1 + b0 + b1);
        }
        VMCNT0();
        if (l == 0) stu(&p2w[w], (unsigned)T);                      // slots <= T-1 valid
        // ---- future: straight mode (serial chain needs same-step data).
        for (int t = T; t < TOT; ++t) {
            if (t >= S) wait_ge(b_prog, (unsigned)(t - S + 1), cb);
            wait_min4(aw, (unsigned)(t + 1), ca);
            const float* rp = ring1 + (size_t)(t & smask) * HH;
            float hv0 = ld_f(rp + l);
            float hv1 = (l < 36) ? ld_f(rp + 64 + l) : 0.f;
            float a0 = 0.f, a1 = 0.f, b0 = 0.f, b1 = 0.f;
            REP13(DOTC)
            float* wpp = ring2 + (size_t)(t & smask) * ROWS;
            st_wt(wpp + j0, bi0 + a0 + a1);
            if (has2) st_wt(wpp + j1, bi1 + b0 + b1);
            VMCNT0();
            if (l == 0) stu(&p2w[w], (unsigned)(t + 1));
        }
    } else {
        // ================= B: layer-2 recurrence + output =================
        __shared__ __align__(16) float h2s[2][128];
        __shared__ float yp2[2][4];
        const float4* w0p = (const float4*)(wc + (size_t)gj0 * RPAD);
        const float4* w1p = (const float4*)(wc + (size_t)gj1 * RPAD);
        const float wl = gi_lane ? w_lin[cell] : 0.f;
        const float bl = b_lin[0];
        float c2 = 0.f;
        if (tid < 128) { h2s[0][tid] = 0.f; h2s[1][tid] = 0.f; }
        __syncthreads();   // publishes fp16 conversion + h2s init

        unsigned cpB = 0;
        for (int u = 0; u < TOT; ++u) {
            // Emit previous step's y right after its barrier.
            if (tid == 0 && u > 0) {
                const float* yq = yp2[(u - 1) & 1];
                float y = yq[0] + yq[1] + yq[2] + yq[3] + bl;
                stu(b_prog, (unsigned)u);        // ring2 slot u-1 consumed pre-barrier
                if (u - 1 >= T - 1) {
                    st_wt(&y_slot[(u - 1) - (T - 1)], y);
                    VMCNT0();                    // y_slot store acked before flag
                    stu(y_prog, (unsigned)(u - T + 1));
                }
                out[u - 1] = y;
            }
            float hv0 = h2s[u & 1][l];
            float hv1 = h2s[u & 1][64 + l];
            const float* pp = ring2 + (size_t)(u & smask) * ROWS;
            float preA, preB;
            float a0 = 0.f, a1 = 0.f, b0 = 0.f, b1 = 0.f;
            if (u < T) {     // encode: wait first so pre2 load latency hides under dot
                wait_min4(p2w, (unsigned)(u + 1), cpB);
                preA = ld_f(pp + gj0);
                preB = ld_f(pp + gj1);
                REP13(DOTC)
            } else {         // future: local dot first, then wait
                REP13(DOTC)
                wait_min4(p2w, (unsigned)(u + 1), cpB);
                preA = ld_f(pp + gj0);
                preB = ld_f(pp + gj1);
            }
            float accA = preA + a0 + a1;
            float accB = preB + b0 + b1;
            float vA = go_lane ? fast_tanh(accA) : fast_sigm(accA);
            float vB = fast_sigm(accB);
            float gg = __shfl_xor(vA, 32);
            float go = __shfl_xor(vB, 32);
            float py = 0.f;
            if (gi_lane) {
                c2 = fmaf(vB, c2, vA * gg);
                float h = go * fast_tanh(c2);
                h2s[(u + 1) & 1][cell] = h;
                py = h * wl;
            }
            py += __shfl_down(py, 32);
            py += __shfl_down(py, 16);
            py += __shfl_down(py, 8);
            py += __shfl_down(py, 4);
            py += __shfl_down(py, 2);
            py += __shfl_down(py, 1);
            if (l == 0) yp2[u & 1][w] = py;
            bar();
        }
        if (tid == 0) {   // final step's y
            const float* yq = yp2[(TOT - 1) & 1];
            out[TOT - 1] = yq[0] + yq[1] + yq[2] + yq[3] + bl;
        }
    }
}

extern "C" void kernel_launch(void* const* d_in, const int* in_sizes, int n_in,
                              void* d_out, int out_size, void* d_ws, size_t ws_size,
                              hipStream_t stream) {
    const float* input = (const float*)d_in[0];
    const float* enc_h = (const float*)d_in[1];
    const float* enc_c = (const float*)d_in[2];
    const float* w_ih1 = (const float*)d_in[3];
    const float* w_hh1 = (const float*)d_in[4];
    const float* b_ih1 = (const float*)d_in[5];
    const float* b_hh1 = (const float*)d_in[6];
    const float* w_ih2 = (const float*)d_in[7];
    const float* w_hh2 = (const float*)d_in[8];
    const float* b_ih2 = (const float*)d_in[9];
    const float* b_hh2 = (const float*)d_in[10];
    const float* w_lin = (const float*)d_in[11];
    const float* b_lin = (const float*)d_in[12];
    (void)n_in;

    int T = in_sizes[0];
    int F = out_size - T;
    if (F < 0) F = 0;

    // largest power-of-two ring slot count that fits both rings in d_ws
    // (rings start after the 249.6KB converted-weight area)
    int S = 16;
    while ((size_t)OFF_RING + (size_t)S * 2 * (HH + ROWS) * 4 <= ws_size && S < 8192)
        S <<= 1;

    decoder_kernel<<<dim3(3), dim3(NT), 0, stream>>>(
        input, enc_h, enc_c, w_ih1, w_hh1, b_ih1, b_hh1,
        w_ih2, w_hh2, b_ih2, b_hh2, w_lin, b_lin,
        (float*)d_out, (char*)d_ws, T, F, S);
}